// Round 5
// baseline (780.789 us; speedup 1.0000x reference)
//
#include <hip/hip_runtime.h>

// Full MHA: x->QKV proj (bf16 MFMA GEMM) -> flash attention -> out proj.
// bf16 compute, fp32 accumulate.
// R12: R11's 2-q-set LDS-traffic halving WITHOUT the VGPR cliff.
//      R11 post-mortem: 136 VGPR crossed the 128 occupancy step -> 2
//      waves/SIMD, occ 11.5%, dur 269us. LDS-BW theory was right; TLP died.
//      Fixes: (a) QK+softmax per 16-k sub-chunk -> sc live range 32->8 VGPR,
//      (b) defer-max check via PER-LANE max + __all (row-max shfls only in
//          the rare rescale branch); per-lane partial l_i, quad-reduced ONCE
//          after the kv loop (kills 8 DS-shuffles/iter from the LDS pipe),
//      (c) __launch_bounds__(256,4) pins VGPR<=128; sP pair-reused (1KB/wave)
//          -> LDS 40KB. Target: 4 waves/SIMD, LDS-pipe floor ~116us.
// R11: 32 q-rows/wave (2 q-sets), kf/vf read once feed both q-sets.
// R9:  QSCALE folded into Q, Q direct->VGPR, defer-max (T13), setprio (T5).
// R8:  gemm_qkv 256x256 3-buf counted-vmcnt pipeline (T3+T4+T5).

typedef __bf16 bf16;
typedef __bf16 bf16x4 __attribute__((ext_vector_type(4)));
typedef __bf16 bf16x8 __attribute__((ext_vector_type(8)));
typedef float  f32x4  __attribute__((ext_vector_type(4)));

#define S_TOK 2048
#define DMODEL 2048
#define NHEAD 16
#define HDIM 128
#define BH_STRIDE ((size_t)S_TOK * HDIM)   // 262144 elems per (b,h)
#define KT32 (DMODEL / 32)                 // 64 32-k tiles per K
#define TILE_ELEMS 4096                    // 128(m|n) x 32k fragment-linear tile
// 1/sqrt(128) * log2(e) -- folded into Q so flash scores are already log2-scaled
#define QSCALE (0.08838834764831845f * 1.4426950408889634f)

__device__ __forceinline__ void load_lds16(const void* g, void* l) {
  __builtin_amdgcn_global_load_lds((const __attribute__((address_space(1))) void*)g,
                                   (__attribute__((address_space(3))) void*)l,
                                   16, 0, 0);
}

// ---------------- prep kernels ----------------

// Pack x fp32 [8192][2048] -> fragment-linear bf16 tiles:
// apack[(mt*64+kt)*4096 + f*512 + lane*8 + e]
//   = (bf16) x[mt*128 + f*16 + (lane&15)][kt*32 + (lane>>4)*8 + e]
// grid: x = kt (64), y = mt (64)
__global__ __launch_bounds__(256) void pack_a(const float* __restrict__ X,
                                              bf16* __restrict__ dst) {
  __shared__ bf16 lds[128 * 32];
  const int t = threadIdx.x;
  const int kt = blockIdx.x, mt = blockIdx.y;
  const int k0 = kt * 32, m0 = mt * 128;
  // coalesced read: 128 rows x 32k, 8 threads x float4 per row
#pragma unroll
  for (int p = 0; p < 4; ++p) {
    int r = p * 32 + (t >> 3);           // 0..127
    int c = (t & 7) * 4;                 // 0..28
    float4 v = *(const float4*)(X + (size_t)(m0 + r) * DMODEL + k0 + c);
    lds[r * 32 + c + 0] = (bf16)v.x;
    lds[r * 32 + c + 1] = (bf16)v.y;
    lds[r * 32 + c + 2] = (bf16)v.z;
    lds[r * 32 + c + 3] = (bf16)v.w;
  }
  __syncthreads();
  bf16* out = dst + ((size_t)mt * 64 + kt) * TILE_ELEMS;
#pragma unroll
  for (int u = 0; u < 2; ++u) {
    int c = t * 2 + u;                   // chunk 0..511
    int f = c >> 6, lane = c & 63;
    int l16 = lane & 15, q = lane >> 4;
    bf16x8 v;
#pragma unroll
    for (int e = 0; e < 8; ++e)
      v[e] = lds[(f * 16 + l16) * 32 + q * 8 + e];
    *(bf16x8*)(out + (size_t)c * 8) = v;
  }
}

// Pack W fp32 [K=2048][N=2048] row-major into fragment-linear bf16 tiles:
// dst[(nt*64 + kt)*4096 + i_g*512 + quad*128 + l16*8 + e]
//   = (bf16) W[kt*32 + quad*8 + e][nt*128 + i_g*16 + l16]
__global__ __launch_bounds__(256) void pack_w(const float* __restrict__ W,
                                              bf16* __restrict__ dst) {
  __shared__ bf16 lds[32 * 128];
  const int t = threadIdx.x;
  const int kt = blockIdx.x, nt = blockIdx.y;
  const int k0 = kt * 32, n0 = nt * 128;
#pragma unroll
  for (int p = 0; p < 4; ++p) {
    int kl = (t >> 5) + p * 8;
    int nl = (t & 31) * 4;
    float4 v = *(const float4*)(W + (size_t)(k0 + kl) * DMODEL + n0 + nl);
    lds[kl * 128 + nl + 0] = (bf16)v.x;
    lds[kl * 128 + nl + 1] = (bf16)v.y;
    lds[kl * 128 + nl + 2] = (bf16)v.z;
    lds[kl * 128 + nl + 3] = (bf16)v.w;
  }
  __syncthreads();
  bf16* out = dst + ((size_t)nt * KT32 + kt) * TILE_ELEMS;
#pragma unroll
  for (int u = 0; u < 2; ++u) {
    int c = t * 2 + u;
    int i_g = c >> 6, quad = (c >> 4) & 3, l16 = c & 15;
    bf16x8 v;
#pragma unroll
    for (int e = 0; e < 8; ++e)
      v[e] = lds[(quad * 8 + e) * 128 + i_g * 16 + l16];
    *(bf16x8*)(out + (size_t)c * 8) = v;
  }
}

// V reshuffle: vb[bh][s][d] -> vc[bh][s>>3][d][s&7]
__global__ __launch_bounds__(256) void v_chunk(const bf16* __restrict__ vb,
                                               bf16* __restrict__ vc) {
  __shared__ alignas(16) bf16 t[64 * 128];
  const int tid = threadIdx.x;
  const int s0 = blockIdx.x * 64;
  const size_t bhoff = (size_t)blockIdx.y * BH_STRIDE;
  const bf16* src = vb + bhoff + (size_t)s0 * HDIM;
#pragma unroll
  for (int r = 0; r < 4; ++r) {
    int c = r * 256 + tid;
    *(bf16x8*)(t + (size_t)c * 8) = *(const bf16x8*)(src + (size_t)(c >> 4) * HDIM + (c & 15) * 8);
  }
  __syncthreads();
  bf16* dst = vc + bhoff + (size_t)(s0 >> 3) * (HDIM * 8);
#pragma unroll
  for (int r = 0; r < 4; ++r) {
    int c = r * 256 + tid;
    int scl = c >> 7, d = c & 127;
    bf16x8 v;
#pragma unroll
    for (int e = 0; e < 8; ++e) v[e] = t[(size_t)(scl * 8 + e) * HDIM + d];
    *(bf16x8*)(dst + (size_t)scl * (HDIM * 8) + d * 8) = v;
  }
}

// ---------------- gemm_qkv: 256x256 LDS-staged counted-vmcnt pipeline ----------------
// A,B pre-packed fragment-linear (pack_a / pack_w). 8 waves: wm=wave>>2 (2),
// wn=wave&3 (4); per-wave output 128x64 -> acc[8][4] f32x4.
// LDS: 3 buffers x 16384 elems (A: 2x4096 | B: 2x4096). Prefetch distance 2.
// Per K-step (BK=32): vmcnt(4); s_barrier; then 2 phases of
//   {ds_read frags, 2x global_load_lds for step t+2, setprio(1), 16 MFMA}.
// grid: 768 blocks (32 m-tiles x 24 n-tiles), XCD-bijective swizzle.
__global__ __launch_bounds__(512, 2) void gemm_qkv(
    const bf16* __restrict__ apack, const bf16* __restrict__ wpack,
    const float* __restrict__ bq, const float* __restrict__ bk, const float* __restrict__ bv,
    bf16* __restrict__ qc, bf16* __restrict__ kc_, bf16* __restrict__ vb) {
  __shared__ alignas(16) bf16 sBuf[3 * 16384];   // 96 KB
  const int tid = threadIdx.x, wave = tid >> 6, lane = tid & 63;
  const int quad = lane >> 4, l16 = lane & 15;
  const int wm = wave >> 2, wn = wave & 3;

  // XCD-bijective swizzle: 768 wgs = 8 XCDs x 96. Each XCD walks 32 m-tiles
  // per n-panel, 3 consecutive n-panels (3 MB of packed B <= 4 MB XCD L2).
  const int lin = blockIdx.x;
  const int swz = (lin & 7) * 96 + (lin >> 3);
  const int mt = swz & 31, nt = swz >> 5;
  const int m0 = mt * 256, n0 = nt * 256;

  const bf16* srcA0 = apack + (size_t)(mt * 2 + 0) * KT32 * TILE_ELEMS + (size_t)tid * 8;
  const bf16* srcA1 = apack + (size_t)(mt * 2 + 1) * KT32 * TILE_ELEMS + (size_t)tid * 8;
  const bf16* srcB0 = wpack + (size_t)(nt * 2 + 0) * KT32 * TILE_ELEMS + (size_t)tid * 8;
  const bf16* srcB1 = wpack + (size_t)(nt * 2 + 1) * KT32 * TILE_ELEMS + (size_t)tid * 8;

  f32x4 acc[8][4];
  const f32x4 zero = {0.f, 0.f, 0.f, 0.f};
#pragma unroll
  for (int i = 0; i < 8; ++i)
#pragma unroll
    for (int j = 0; j < 4; ++j) acc[i][j] = zero;

  bf16* sD = sBuf + (size_t)tid * 8;   // per-thread staging dst (wave-uniform base + lane*16)

  // prologue: stage K-steps 0 -> buf0, 1 -> buf1 (8 loads outstanding)
  load_lds16(srcA0, sD);
  load_lds16(srcA1, sD + 4096);
  load_lds16(srcB0, sD + 8192);
  load_lds16(srcB1, sD + 12288);
  load_lds16(srcA0 + TILE_ELEMS, sD + 16384);
  load_lds16(srcA1 + TILE_ELEMS, sD + 16384 + 4096);
  load_lds16(srcB0 + TILE_ELEMS, sD + 16384 + 8192);
  load_lds16(srcB1 + TILE_ELEMS, sD + 16384 + 12288);

  // per-wave LDS fragment bases (lane-contiguous ds_read_b128, conflict-free)
  const bf16* ldsA = sBuf + (size_t)wm * 4096 + (size_t)lane * 8;
  const bf16* ldsB = sBuf + 8192 + (size_t)(wn >> 1) * 4096
                   + (size_t)((wn & 1) * 4) * 512 + (size_t)lane * 8;

  int buf = 0, nbuf = 2;
#pragma unroll 1
  for (int t = 0; t < KT32; ++t) {
    // counted wait: all but the 4 newest vmem ops complete -> this K-step's
    // buffer is fully staged; the next step's 4 loads stay in flight.
    if (t == KT32 - 1) { asm volatile("s_waitcnt vmcnt(0)" ::: "memory"); }
    else               { asm volatile("s_waitcnt vmcnt(4)" ::: "memory"); }
    __builtin_amdgcn_s_barrier();
    asm volatile("" ::: "memory");   // keep LDS reads below the barrier

    const bf16* bA = ldsA + buf * 16384;
    const bf16* bB = ldsB + buf * 16384;

    bf16x8 bfr[4], afr[4];
#pragma unroll
    for (int j = 0; j < 4; ++j) bfr[j] = *(const bf16x8*)(bB + (size_t)j * 512);
#pragma unroll
    for (int i = 0; i < 4; ++i) afr[i] = *(const bf16x8*)(bA + (size_t)i * 512);
    if (t < KT32 - 2) {            // stage A-half of K-step t+2
      bf16* d = sD + nbuf * 16384;
      load_lds16(srcA0 + (size_t)(t + 2) * TILE_ELEMS, d);
      load_lds16(srcA1 + (size_t)(t + 2) * TILE_ELEMS, d + 4096);
    }
    __builtin_amdgcn_s_setprio(1);
#pragma unroll
    for (int i = 0; i < 4; ++i)
#pragma unroll
      for (int j = 0; j < 4; ++j)
        acc[i][j] = __builtin_amdgcn_mfma_f32_16x16x32_bf16(bfr[j], afr[i], acc[i][j], 0, 0, 0);
    __builtin_amdgcn_s_setprio(0);

#pragma unroll
    for (int i = 0; i < 4; ++i) afr[i] = *(const bf16x8*)(bA + (size_t)(4 + i) * 512);
    if (t < KT32 - 2) {            // stage B-half of K-step t+2
      bf16* d = sD + nbuf * 16384;
      load_lds16(srcB0 + (size_t)(t + 2) * TILE_ELEMS, d + 8192);
      load_lds16(srcB1 + (size_t)(t + 2) * TILE_ELEMS, d + 12288);
    }
    __builtin_amdgcn_s_setprio(1);
#pragma unroll
    for (int i = 0; i < 4; ++i)
#pragma unroll
      for (int j = 0; j < 4; ++j)
        acc[4 + i][j] = __builtin_amdgcn_mfma_f32_16x16x32_bf16(bfr[j], afr[i], acc[4 + i][j], 0, 0, 0);
    __builtin_amdgcn_s_setprio(0);

    buf  = (buf  == 2) ? 0 : buf  + 1;
    nbuf = (nbuf == 2) ? 0 : nbuf + 1;
  }

  // epilogue (fragment->element mapping verified in R7). Q gets QSCALE folded
  // so flash scores are already in log2 units (saves a VALU mul per score).
  const float* bias; bf16* dst; int chunked; float oscale;
  if (n0 < 2048)      { bias = bq; dst = qc;  chunked = 1; oscale = QSCALE; }
  else if (n0 < 4096) { bias = bk; dst = kc_; chunked = 1; oscale = 1.0f; }
  else                { bias = bv; dst = vb;  chunked = 0; oscale = 1.0f; }
  const int nb = n0 & 2047;
  const int rw = wm * 128, cw = wn * 64;
#pragma unroll
  for (int i = 0; i < 8; ++i) {
    int m = m0 + rw + i * 16 + l16;
    int b = m >> 11, s = m & 2047;
#pragma unroll
    for (int j = 0; j < 4; ++j) {
      int n = nb + cw + j * 16 + quad * 4;
      int h = n >> 7, d = n & 127;
      bf16x4 v;
#pragma unroll
      for (int r = 0; r < 4; ++r) v[r] = (bf16)((acc[i][j][r] + bias[n + r]) * oscale);
      size_t bhoff = (size_t)(b * NHEAD + h) * BH_STRIDE;
      if (chunked)
        *(bf16x4*)(dst + bhoff + (size_t)(d >> 3) * (S_TOK * 8) + (size_t)s * 8 + (d & 7)) = v;
      else
        *(bf16x4*)(dst + bhoff + (size_t)s * HDIM + d) = v;
    }
  }
}

// ---------------- gemm_out: R5 core (A row-major via LDS dbuf, B direct) ----------------
__device__ __forceinline__ void gemm_core_lds(const bf16* __restrict__ A,       // [M][2048]
                                              const bf16* __restrict__ wpanel,  // packed n-panel
                                              int m0, bf16* sA, f32x4 acc[4][4]) {
  const int tid = threadIdx.x;
  const int wave = tid >> 6, lane = tid & 63;
  const int quad = lane >> 4, l16 = lane & 15;
  const int rw = (wave >> 1) * 64;

  const f32x4 zero = {0.f, 0.f, 0.f, 0.f};
#pragma unroll
  for (int i = 0; i < 4; ++i)
#pragma unroll
    for (int j = 0; j < 4; ++j) acc[i][j] = zero;

  const int kb0 = tid >> 7;
  const int row = tid & 127;
  const bf16* a0 = A + (size_t)(m0 + row) * DMODEL + kb0 * 8;
  const bf16* a1 = a0 + 16;
  const bf16* wb = wpanel + (size_t)(wave & 1) * 4 * 512 + (size_t)lane * 8;

  load_lds16(a0, sA + tid * 8); load_lds16(a1, sA + (256 + tid) * 8);
  a0 += 32; a1 += 32;
  bf16x8 wfc[4], wfn[4];
#pragma unroll
  for (int j = 0; j < 4; ++j)
    wfc[j] = *(const bf16x8*)(wb + (size_t)j * 512);

#pragma unroll 2
  for (int kt = 0; kt < KT32; ++kt) {
    __syncthreads();
    const int cur = kt & 1, nxt = cur ^ 1;
    if (kt + 1 < KT32) {
      load_lds16(a0, sA + (nxt * 512 + tid) * 8);
      load_lds16(a1, sA + (nxt * 512 + 256 + tid) * 8);
      a0 += 32; a1 += 32;
      const bf16* wn = wb + (size_t)(kt + 1) * TILE_ELEMS;
#pragma unroll
      for (int j = 0; j < 4; ++j)
        wfn[j] = *(const bf16x8*)(wn + (size_t)j * 512);
    }
    const bf16* sAc = sA + cur * 4096;
    bf16x8 xf[4];
#pragma unroll
    for (int i = 0; i < 4; ++i)
      xf[i] = *(const bf16x8*)(sAc + ((size_t)quad * 128 + rw + i * 16 + l16) * 8);
#pragma unroll
    for (int i = 0; i < 4; ++i)
#pragma unroll
      for (int j = 0; j < 4; ++j)
        acc[i][j] = __builtin_amdgcn_mfma_f32_16x16x32_bf16(wfc[j], xf[i], acc[i][j], 0, 0, 0);
#pragma unroll
    for (int j = 0; j < 4; ++j) wfc[j] = wfn[j];
  }
}

// output projection: fp32 out, fused bias.  grid: x = m-tile (64), y = n-tile (16)
__global__ __launch_bounds__(256) void gemm_out(
    const bf16* __restrict__ A, const bf16* __restrict__ wpack,
    const float* __restrict__ bo, float* __restrict__ out) {
  __shared__ alignas(16) bf16 sA[2 * 4096];
  const int m0 = blockIdx.x * 128, n0 = blockIdx.y * 128;
  f32x4 acc[4][4];
  gemm_core_lds(A, wpack + (size_t)blockIdx.y * KT32 * TILE_ELEMS, m0, sA, acc);

  const int tid = threadIdx.x, wave = tid >> 6, lane = tid & 63;
  const int quad = lane >> 4, l16 = lane & 15;
  const int rw = (wave >> 1) * 64, cw = (wave & 1) * 64;
#pragma unroll
  for (int i = 0; i < 4; ++i) {
    int m = m0 + rw + i * 16 + l16;
#pragma unroll
    for (int j = 0; j < 4; ++j) {
      int n = n0 + cw + j * 16 + quad * 4;
      f32x4 v = acc[i][j];
#pragma unroll
      for (int r = 0; r < 4; ++r) v[r] += bo[n + r];
      *(f32x4*)(out + (size_t)m * DMODEL + n) = v;
    }
  }
}

// ---------------- flash attention ----------------
// R12: 4 waves x 32 q-rows (2 q-sets), KVBLK=64 processed as 4x16-k
// sub-chunks (sc live range = 8 VGPR). PV per 32-k pair. Per-lane defer-max
// check (__all over lane-max; row-max shfls only in rare rescale branch);
// per-lane partial l_i reduced once after the kv loop. kf/vf read once feed
// both q-sets. LDS: sK 16 + sV 16 + sP 8 = 40KB. Target <=128 VGPR.
__global__ __launch_bounds__(256, 4) void flash_kernel(
    const bf16* __restrict__ qc, const bf16* __restrict__ kcg,
    const bf16* __restrict__ vcg, bf16* __restrict__ ob) {
  __shared__ alignas(16) bf16 sK[16 * 64 * 8];   // 16KB [kc][s][8]
  __shared__ alignas(16) bf16 sV[8 * 128 * 8];   // 16KB [scl][d][8]
  __shared__ alignas(16) bf16 sP[4 * 1024];      // 8KB: per wave 1KB (2qs x 512)

  const int tid = threadIdx.x, wave = tid >> 6, lane = tid & 63;
  const int quad = lane >> 4, l16 = lane & 15;
  const int bh = blockIdx.y;
  const int q0 = blockIdx.x * 128;               // block covers 128 q-rows

  const bf16* Qg = qc  + (size_t)bh * BH_STRIDE;
  const bf16* Kg = kcg + (size_t)bh * BH_STRIDE;
  const bf16* Vg = vcg + (size_t)bh * BH_STRIDE;

  // Q fragments straight from global (loop-invariant, 32 VGPR)
  bf16x8 qf[2][4];
#pragma unroll
  for (int qs = 0; qs < 2; ++qs)
#pragma unroll
    for (int ks = 0; ks < 4; ++ks)
      qf[qs][ks] = *(const bf16x8*)(Qg + (size_t)(ks * 4 + quad) * (S_TOK * 8)
                                       + (size_t)(q0 + wave * 32 + qs * 16 + l16) * 8);

  bf16* sPw = sP + wave * 1024;

  float m_i[2] = {-1e30f, -1e30f};
  float l_i[2] = {0.f, 0.f};               // per-lane partial row sums
  f32x4 o[2][8];
  const f32x4 zero = {0.f, 0.f, 0.f, 0.f};
#pragma unroll
  for (int qs = 0; qs < 2; ++qs)
#pragma unroll
    for (int dt = 0; dt < 8; ++dt) o[qs][dt] = zero;

#pragma unroll 1
  for (int kv = 0; kv < S_TOK; kv += 64) {
    __syncthreads();
#pragma unroll
    for (int r = 0; r < 4; ++r) {
      int c = r * 256 + tid;
      load_lds16(Kg + (size_t)(c >> 6) * (S_TOK * 8) + (size_t)(kv + (c & 63)) * 8,
                 sK + (size_t)c * 8);
    }
#pragma unroll
    for (int r = 0; r < 4; ++r) {
      int c = r * 256 + tid;
      load_lds16(Vg + (size_t)((kv >> 3) + (c >> 7)) * (HDIM * 8) + (size_t)(c & 127) * 8,
                 sV + (size_t)c * 8);
    }
    __syncthreads();

#pragma unroll
    for (int pp = 0; pp < 2; ++pp) {       // 32-k PV pair
#pragma unroll
      for (int sub = 0; sub < 2; ++sub) {  // 16-k QK/softmax sub-chunk
        const int ch = pp * 2 + sub;
        f32x4 sc0 = zero, sc1 = zero;
        __builtin_amdgcn_s_setprio(1);
#pragma unroll
        for (int ks = 0; ks < 4; ++ks) {
          bf16x8 kf = *(const bf16x8*)(sK + ((size_t)(ks * 4 + quad) * 64 + ch * 16 + l16) * 8);
          sc0 = __builtin_amdgcn_mfma_f32_16x16x32_bf16(kf, qf[0][ks], sc0, 0, 0, 0);
          sc1 = __builtin_amdgcn_mfma_f32_16x16x32_bf16(kf, qf[1][ks], sc1, 0, 0, 0);
        }
        __builtin_amdgcn_s_setprio(0);

        // per-LANE max (no shfl on fast path)
        float t0 = fmaxf(fmaxf(sc0[0], sc0[1]), fmaxf(sc0[2], sc0[3]));
        float t1 = fmaxf(fmaxf(sc1[0], sc1[1]), fmaxf(sc1[2], sc1[3]));
        bool ok = (t0 - m_i[0] <= 8.0f) && (t1 - m_i[1] <= 8.0f);
        if (!__all(ok)) {
          // rare: full row-max across quads, rescale running state
          float r0 = fmaxf(t0, __shfl_xor(t0, 16)); r0 = fmaxf(r0, __shfl_xor(r0, 32));
          float r1 = fmaxf(t1, __shfl_xor(t1, 16)); r1 = fmaxf(r1, __shfl_xor(r1, 32));
          float m0n = fmaxf(m_i[0], r0), a0 = __builtin_amdgcn_exp2f(m_i[0] - m0n);
          float m1n = fmaxf(m_i[1], r1), a1 = __builtin_amdgcn_exp2f(m_i[1] - m1n);
          m_i[0] = m0n; m_i[1] = m1n;
          l_i[0] *= a0; l_i[1] *= a1;
#pragma unroll
          for (int dt = 0; dt < 8; ++dt) { o[0][dt] = o[0][dt] * a0; o[1][dt] = o[1][dt] * a1; }
        }

        // exp + per-lane partial sum + P store (P bounded by 2^8)
        bf16x4 pv0, pv1;
        float s00, s01, s10, s11;
        {
          float p0 = __builtin_amdgcn_exp2f(sc0[0] - m_i[0]);
          float p1 = __builtin_amdgcn_exp2f(sc0[1] - m_i[0]);
          float p2 = __builtin_amdgcn_exp2f(sc0[2] - m_i[0]);
          float p3 = __builtin_amdgcn_exp2f(sc0[3] - m_i[0]);
          pv0[0] = (bf16)p0; pv0[1] = (bf16)p1; pv0[2] = (bf16)p2; pv0[3] = (bf16)p3;
          s00 = p0 + p1; s01 = p2 + p3;
        }
        {
          float p0 = __builtin_amdgcn_exp2f(sc1[0] - m_i[1]);
          float p1 = __builtin_amdgcn_exp2f(sc1[1] - m_i[1]);
          float p2 = __builtin_amdgcn_exp2f(sc1[2] - m_i[1]);
          float p3 = __builtin_amdgcn_exp2f(sc1[3] - m_i[1]);
          pv1[0] = (bf16)p0; pv1[1] = (bf16)p1; pv1[2] = (bf16)p2; pv1[3] = (bf16)p3;
          s10 = p0 + p1; s11 = p2 + p3;
        }
        l_i[0] += s00 + s01;
        l_i[1] += s10 + s11;
        const int prow = (sub * 2 + (quad >> 1)) * 128 + l16 * 8 + (quad & 1) * 4;
        *(bf16x4*)(sPw + prow) = pv0;
        *(bf16x4*)(sPw + 512 + prow) = pv1;
      }

      // PV over the 32-k pair: vf read once, feeds both q-sets
      bf16x8 pf0 = *(const bf16x8*)(sPw + (size_t)(quad * 128 + l16 * 8));
      bf16x8 pf1 = *(const bf16x8*)(sPw + 512 + (size_t)(quad * 128 + l16 * 8));
      __builtin_amdgcn_s_setprio(1);
#pragma unroll
      for (int dt = 0; dt < 8; ++dt) {
        bf16x8 vf = *(const bf16x8*)(sV + ((size_t)(pp * 4 + quad) * 128 + dt * 16 + l16) * 8);
        o[0][dt] = __builtin_amdgcn_mfma_f32_16x16x32_bf16(vf, pf0, o[0][dt], 0, 0, 0);
        o[1][dt] = __builtin_amdgcn_mfma_f32_16x16x32_bf16(vf, pf1, o[1][dt], 0, 0, 0);
      }
      __builtin_amdgcn_s_setprio(0);
    }
  }

  // final cross-quad row-sum (the ONLY shuffles on the softmax fast path)
  int b = bh >> 4, h = bh & 15;
#pragma unroll
  for (int qs = 0; qs < 2; ++qs) {
    float l = l_i[qs];
    l += __shfl_xor(l, 16);
    l += __shfl_xor(l, 32);
    float inv = 1.0f / l;
    int s = q0 + wave * 32 + qs * 16 + l16;
    bf16* orow = ob + ((size_t)(b * S_TOK + s) * DMODEL + h * HDIM);
#pragma unroll
    for (int dt = 0; dt < 8; ++dt) {
      bf16x4 v;
#pragma unroll
      for (int r = 0; r < 4; ++r) v[r] = (bf16)(o[qs][dt][r] * inv);
      *(bf16x4*)(orow + dt * 16 + quad * 4) = v;
    }
  }
}

// ---------------- launch ----------------

extern "C" void kernel_launch(void* const* d_in, const int* in_sizes, int n_in,
                              void* d_out, int out_size, void* d_ws, size_t ws_size,
                              hipStream_t stream) {
  const float* x  = (const float*)d_in[0];
  const float* Wq = (const float*)d_in[2];
  const float* bq = (const float*)d_in[3];
  const float* Wk = (const float*)d_in[4];
  const float* bk = (const float*)d_in[5];
  const float* Wv = (const float*)d_in[6];
  const float* bv = (const float*)d_in[7];
  const float* Wo = (const float*)d_in[8];
  const float* bo = (const float*)d_in[9];
  float* out = (float*)d_out;

  const size_t M = 4 * (size_t)S_TOK;          // 8192
  const size_t SZ_TOK = M * DMODEL * 2;        // 33.5MB bf16 token-shaped buffer
  const size_t SZ_WMAT = (size_t)16 * KT32 * TILE_ELEMS * 2;

  char* p = (char*)d_ws;
  bf16* ap  = (bf16*)p; p += SZ_TOK;           // packed activations; reused as ob
  bf16* wp  = (bf16*)p; p += 3 * SZ_WMAT;      // packed Wq|Wk|Wv
  bf16* wop = (bf16*)p; p += SZ_WMAT;          // packed Wo
  bf16* qc  = (bf16*)p; p += SZ_TOK;
  bf16* kc  = (bf16*)p; p += SZ_TOK;
  bf16* vb  = (bf16*)p; p += SZ_TOK;
  bf16* vc  = (bf16*)p; p += SZ_TOK;
  bf16* ob  = ap;   // apack dead after gemm_qkv; flash writes ob here

  pack_a<<<dim3(64, 64), 256, 0, stream>>>(x, ap);
  pack_w<<<dim3(KT32, 16), 256, 0, stream>>>(Wq, wp);
  pack_w<<<dim3(KT32, 16), 256, 0, stream>>>(Wk, wp + SZ_WMAT / 2);
  pack_w<<<dim3(KT32, 16), 256, 0, stream>>>(Wv, wp + SZ_WMAT);
  pack_w<<<dim3(KT32, 16), 256, 0, stream>>>(Wo, wop);

  gemm_qkv<<<dim3(768), dim3(512), 0, stream>>>(ap, wp, bq, bk, bv, qc, kc, vb);
  v_chunk<<<dim3(32, 64), 256, 0, stream>>>(vb, vc);
  flash_kernel<<<dim3(16, 64), 256, 0, stream>>>(qc, kc, vc, ob);
  gemm_out<<<dim3(64, 16), 256, 0, stream>>>(ob, wop, bo, out);
}

// Round 6
// 692.532 us; speedup vs baseline: 1.1274x; 1.1274x over previous
//
#include <hip/hip_runtime.h>

// Full MHA: x->QKV proj (bf16 MFMA GEMM) -> flash attention -> out proj.
// bf16 compute, fp32 accumulate.
// R13: un-spill R12. R12 post-mortem: __launch_bounds__(256,4) forced the
//      allocator to 64 VGPR -> o[2][8] accumulators spilled to scratch
//      (VGPR=64 < 64-reg acc footprint; FETCH +68MB, WRITE +20MB of scratch
//      traffic; latency-bound, dur 275us). The R12 live-range surgery is
//      kept (sc 32->8 VGPR, per-lane defer-max, post-loop l_i reduce);
//      natural usage ~115-125 VGPR -> 4 waves/SIMD WITHOUT forcing.
//      One-line fix: __launch_bounds__(256) (no min-wave clamp).
// R12: QK+softmax per 16-k sub-chunk; per-lane defer-max fast path;
//      per-lane partial l_i reduced once after kv loop; LDS 40KB.
// R11: 32 q-rows/wave (2 q-sets), kf/vf read once feed both q-sets
//      (halves LDS read traffic per output -- the LDS-BW lever).
// R9:  QSCALE folded into Q, Q direct->VGPR, defer-max (T13), setprio (T5).
// R8:  gemm_qkv 256x256 3-buf counted-vmcnt pipeline (T3+T4+T5).

typedef __bf16 bf16;
typedef __bf16 bf16x4 __attribute__((ext_vector_type(4)));
typedef __bf16 bf16x8 __attribute__((ext_vector_type(8)));
typedef float  f32x4  __attribute__((ext_vector_type(4)));

#define S_TOK 2048
#define DMODEL 2048
#define NHEAD 16
#define HDIM 128
#define BH_STRIDE ((size_t)S_TOK * HDIM)   // 262144 elems per (b,h)
#define KT32 (DMODEL / 32)                 // 64 32-k tiles per K
#define TILE_ELEMS 4096                    // 128(m|n) x 32k fragment-linear tile
// 1/sqrt(128) * log2(e) -- folded into Q so flash scores are already log2-scaled
#define QSCALE (0.08838834764831845f * 1.4426950408889634f)

__device__ __forceinline__ void load_lds16(const void* g, void* l) {
  __builtin_amdgcn_global_load_lds((const __attribute__((address_space(1))) void*)g,
                                   (__attribute__((address_space(3))) void*)l,
                                   16, 0, 0);
}

// ---------------- prep kernels ----------------

// Pack x fp32 [8192][2048] -> fragment-linear bf16 tiles:
// apack[(mt*64+kt)*4096 + f*512 + lane*8 + e]
//   = (bf16) x[mt*128 + f*16 + (lane&15)][kt*32 + (lane>>4)*8 + e]
// grid: x = kt (64), y = mt (64)
__global__ __launch_bounds__(256) void pack_a(const float* __restrict__ X,
                                              bf16* __restrict__ dst) {
  __shared__ bf16 lds[128 * 32];
  const int t = threadIdx.x;
  const int kt = blockIdx.x, mt = blockIdx.y;
  const int k0 = kt * 32, m0 = mt * 128;
  // coalesced read: 128 rows x 32k, 8 threads x float4 per row
#pragma unroll
  for (int p = 0; p < 4; ++p) {
    int r = p * 32 + (t >> 3);           // 0..127
    int c = (t & 7) * 4;                 // 0..28
    float4 v = *(const float4*)(X + (size_t)(m0 + r) * DMODEL + k0 + c);
    lds[r * 32 + c + 0] = (bf16)v.x;
    lds[r * 32 + c + 1] = (bf16)v.y;
    lds[r * 32 + c + 2] = (bf16)v.z;
    lds[r * 32 + c + 3] = (bf16)v.w;
  }
  __syncthreads();
  bf16* out = dst + ((size_t)mt * 64 + kt) * TILE_ELEMS;
#pragma unroll
  for (int u = 0; u < 2; ++u) {
    int c = t * 2 + u;                   // chunk 0..511
    int f = c >> 6, lane = c & 63;
    int l16 = lane & 15, q = lane >> 4;
    bf16x8 v;
#pragma unroll
    for (int e = 0; e < 8; ++e)
      v[e] = lds[(f * 16 + l16) * 32 + q * 8 + e];
    *(bf16x8*)(out + (size_t)c * 8) = v;
  }
}

// Pack W fp32 [K=2048][N=2048] row-major into fragment-linear bf16 tiles:
// dst[(nt*64 + kt)*4096 + i_g*512 + quad*128 + l16*8 + e]
//   = (bf16) W[kt*32 + quad*8 + e][nt*128 + i_g*16 + l16]
__global__ __launch_bounds__(256) void pack_w(const float* __restrict__ W,
                                              bf16* __restrict__ dst) {
  __shared__ bf16 lds[32 * 128];
  const int t = threadIdx.x;
  const int kt = blockIdx.x, nt = blockIdx.y;
  const int k0 = kt * 32, n0 = nt * 128;
#pragma unroll
  for (int p = 0; p < 4; ++p) {
    int kl = (t >> 5) + p * 8;
    int nl = (t & 31) * 4;
    float4 v = *(const float4*)(W + (size_t)(k0 + kl) * DMODEL + n0 + nl);
    lds[kl * 128 + nl + 0] = (bf16)v.x;
    lds[kl * 128 + nl + 1] = (bf16)v.y;
    lds[kl * 128 + nl + 2] = (bf16)v.z;
    lds[kl * 128 + nl + 3] = (bf16)v.w;
  }
  __syncthreads();
  bf16* out = dst + ((size_t)nt * KT32 + kt) * TILE_ELEMS;
#pragma unroll
  for (int u = 0; u < 2; ++u) {
    int c = t * 2 + u;
    int i_g = c >> 6, quad = (c >> 4) & 3, l16 = c & 15;
    bf16x8 v;
#pragma unroll
    for (int e = 0; e < 8; ++e)
      v[e] = lds[(quad * 8 + e) * 128 + i_g * 16 + l16];
    *(bf16x8*)(out + (size_t)c * 8) = v;
  }
}

// V reshuffle: vb[bh][s][d] -> vc[bh][s>>3][d][s&7]
__global__ __launch_bounds__(256) void v_chunk(const bf16* __restrict__ vb,
                                               bf16* __restrict__ vc) {
  __shared__ alignas(16) bf16 t[64 * 128];
  const int tid = threadIdx.x;
  const int s0 = blockIdx.x * 64;
  const size_t bhoff = (size_t)blockIdx.y * BH_STRIDE;
  const bf16* src = vb + bhoff + (size_t)s0 * HDIM;
#pragma unroll
  for (int r = 0; r < 4; ++r) {
    int c = r * 256 + tid;
    *(bf16x8*)(t + (size_t)c * 8) = *(const bf16x8*)(src + (size_t)(c >> 4) * HDIM + (c & 15) * 8);
  }
  __syncthreads();
  bf16* dst = vc + bhoff + (size_t)(s0 >> 3) * (HDIM * 8);
#pragma unroll
  for (int r = 0; r < 4; ++r) {
    int c = r * 256 + tid;
    int scl = c >> 7, d = c & 127;
    bf16x8 v;
#pragma unroll
    for (int e = 0; e < 8; ++e) v[e] = t[(size_t)(scl * 8 + e) * HDIM + d];
    *(bf16x8*)(dst + (size_t)scl * (HDIM * 8) + d * 8) = v;
  }
}

// ---------------- gemm_qkv: 256x256 LDS-staged counted-vmcnt pipeline ----------------
// A,B pre-packed fragment-linear (pack_a / pack_w). 8 waves: wm=wave>>2 (2),
// wn=wave&3 (4); per-wave output 128x64 -> acc[8][4] f32x4.
// LDS: 3 buffers x 16384 elems (A: 2x4096 | B: 2x4096). Prefetch distance 2.
// Per K-step (BK=32): vmcnt(4); s_barrier; then 2 phases of
//   {ds_read frags, 2x global_load_lds for step t+2, setprio(1), 16 MFMA}.
// grid: 768 blocks (32 m-tiles x 24 n-tiles), XCD-bijective swizzle.
__global__ __launch_bounds__(512, 2) void gemm_qkv(
    const bf16* __restrict__ apack, const bf16* __restrict__ wpack,
    const float* __restrict__ bq, const float* __restrict__ bk, const float* __restrict__ bv,
    bf16* __restrict__ qc, bf16* __restrict__ kc_, bf16* __restrict__ vb) {
  __shared__ alignas(16) bf16 sBuf[3 * 16384];   // 96 KB
  const int tid = threadIdx.x, wave = tid >> 6, lane = tid & 63;
  const int quad = lane >> 4, l16 = lane & 15;
  const int wm = wave >> 2, wn = wave & 3;

  // XCD-bijective swizzle: 768 wgs = 8 XCDs x 96. Each XCD walks 32 m-tiles
  // per n-panel, 3 consecutive n-panels (3 MB of packed B <= 4 MB XCD L2).
  const int lin = blockIdx.x;
  const int swz = (lin & 7) * 96 + (lin >> 3);
  const int mt = swz & 31, nt = swz >> 5;
  const int m0 = mt * 256, n0 = nt * 256;

  const bf16* srcA0 = apack + (size_t)(mt * 2 + 0) * KT32 * TILE_ELEMS + (size_t)tid * 8;
  const bf16* srcA1 = apack + (size_t)(mt * 2 + 1) * KT32 * TILE_ELEMS + (size_t)tid * 8;
  const bf16* srcB0 = wpack + (size_t)(nt * 2 + 0) * KT32 * TILE_ELEMS + (size_t)tid * 8;
  const bf16* srcB1 = wpack + (size_t)(nt * 2 + 1) * KT32 * TILE_ELEMS + (size_t)tid * 8;

  f32x4 acc[8][4];
  const f32x4 zero = {0.f, 0.f, 0.f, 0.f};
#pragma unroll
  for (int i = 0; i < 8; ++i)
#pragma unroll
    for (int j = 0; j < 4; ++j) acc[i][j] = zero;

  bf16* sD = sBuf + (size_t)tid * 8;   // per-thread staging dst (wave-uniform base + lane*16)

  // prologue: stage K-steps 0 -> buf0, 1 -> buf1 (8 loads outstanding)
  load_lds16(srcA0, sD);
  load_lds16(srcA1, sD + 4096);
  load_lds16(srcB0, sD + 8192);
  load_lds16(srcB1, sD + 12288);
  load_lds16(srcA0 + TILE_ELEMS, sD + 16384);
  load_lds16(srcA1 + TILE_ELEMS, sD + 16384 + 4096);
  load_lds16(srcB0 + TILE_ELEMS, sD + 16384 + 8192);
  load_lds16(srcB1 + TILE_ELEMS, sD + 16384 + 12288);

  // per-wave LDS fragment bases (lane-contiguous ds_read_b128, conflict-free)
  const bf16* ldsA = sBuf + (size_t)wm * 4096 + (size_t)lane * 8;
  const bf16* ldsB = sBuf + 8192 + (size_t)(wn >> 1) * 4096
                   + (size_t)((wn & 1) * 4) * 512 + (size_t)lane * 8;

  int buf = 0, nbuf = 2;
#pragma unroll 1
  for (int t = 0; t < KT32; ++t) {
    // counted wait: all but the 4 newest vmem ops complete -> this K-step's
    // buffer is fully staged; the next step's 4 loads stay in flight.
    if (t == KT32 - 1) { asm volatile("s_waitcnt vmcnt(0)" ::: "memory"); }
    else               { asm volatile("s_waitcnt vmcnt(4)" ::: "memory"); }
    __builtin_amdgcn_s_barrier();
    asm volatile("" ::: "memory");   // keep LDS reads below the barrier

    const bf16* bA = ldsA + buf * 16384;
    const bf16* bB = ldsB + buf * 16384;

    bf16x8 bfr[4], afr[4];
#pragma unroll
    for (int j = 0; j < 4; ++j) bfr[j] = *(const bf16x8*)(bB + (size_t)j * 512);
#pragma unroll
    for (int i = 0; i < 4; ++i) afr[i] = *(const bf16x8*)(bA + (size_t)i * 512);
    if (t < KT32 - 2) {            // stage A-half of K-step t+2
      bf16* d = sD + nbuf * 16384;
      load_lds16(srcA0 + (size_t)(t + 2) * TILE_ELEMS, d);
      load_lds16(srcA1 + (size_t)(t + 2) * TILE_ELEMS, d + 4096);
    }
    __builtin_amdgcn_s_setprio(1);
#pragma unroll
    for (int i = 0; i < 4; ++i)
#pragma unroll
      for (int j = 0; j < 4; ++j)
        acc[i][j] = __builtin_amdgcn_mfma_f32_16x16x32_bf16(bfr[j], afr[i], acc[i][j], 0, 0, 0);
    __builtin_amdgcn_s_setprio(0);

#pragma unroll
    for (int i = 0; i < 4; ++i) afr[i] = *(const bf16x8*)(bA + (size_t)(4 + i) * 512);
    if (t < KT32 - 2) {            // stage B-half of K-step t+2
      bf16* d = sD + nbuf * 16384;
      load_lds16(srcB0 + (size_t)(t + 2) * TILE_ELEMS, d + 8192);
      load_lds16(srcB1 + (size_t)(t + 2) * TILE_ELEMS, d + 12288);
    }
    __builtin_amdgcn_s_setprio(1);
#pragma unroll
    for (int i = 0; i < 4; ++i)
#pragma unroll
      for (int j = 0; j < 4; ++j)
        acc[4 + i][j] = __builtin_amdgcn_mfma_f32_16x16x32_bf16(bfr[j], afr[i], acc[4 + i][j], 0, 0, 0);
    __builtin_amdgcn_s_setprio(0);

    buf  = (buf  == 2) ? 0 : buf  + 1;
    nbuf = (nbuf == 2) ? 0 : nbuf + 1;
  }

  // epilogue (fragment->element mapping verified in R7). Q gets QSCALE folded
  // so flash scores are already in log2 units (saves a VALU mul per score).
  const float* bias; bf16* dst; int chunked; float oscale;
  if (n0 < 2048)      { bias = bq; dst = qc;  chunked = 1; oscale = QSCALE; }
  else if (n0 < 4096) { bias = bk; dst = kc_; chunked = 1; oscale = 1.0f; }
  else                { bias = bv; dst = vb;  chunked = 0; oscale = 1.0f; }
  const int nb = n0 & 2047;
  const int rw = wm * 128, cw = wn * 64;
#pragma unroll
  for (int i = 0; i < 8; ++i) {
    int m = m0 + rw + i * 16 + l16;
    int b = m >> 11, s = m & 2047;
#pragma unroll
    for (int j = 0; j < 4; ++j) {
      int n = nb + cw + j * 16 + quad * 4;
      int h = n >> 7, d = n & 127;
      bf16x4 v;
#pragma unroll
      for (int r = 0; r < 4; ++r) v[r] = (bf16)((acc[i][j][r] + bias[n + r]) * oscale);
      size_t bhoff = (size_t)(b * NHEAD + h) * BH_STRIDE;
      if (chunked)
        *(bf16x4*)(dst + bhoff + (size_t)(d >> 3) * (S_TOK * 8) + (size_t)s * 8 + (d & 7)) = v;
      else
        *(bf16x4*)(dst + bhoff + (size_t)s * HDIM + d) = v;
    }
  }
}

// ---------------- gemm_out: R5 core (A row-major via LDS dbuf, B direct) ----------------
__device__ __forceinline__ void gemm_core_lds(const bf16* __restrict__ A,       // [M][2048]
                                              const bf16* __restrict__ wpanel,  // packed n-panel
                                              int m0, bf16* sA, f32x4 acc[4][4]) {
  const int tid = threadIdx.x;
  const int wave = tid >> 6, lane = tid & 63;
  const int quad = lane >> 4, l16 = lane & 15;
  const int rw = (wave >> 1) * 64;

  const f32x4 zero = {0.f, 0.f, 0.f, 0.f};
#pragma unroll
  for (int i = 0; i < 4; ++i)
#pragma unroll
    for (int j = 0; j < 4; ++j) acc[i][j] = zero;

  const int kb0 = tid >> 7;
  const int row = tid & 127;
  const bf16* a0 = A + (size_t)(m0 + row) * DMODEL + kb0 * 8;
  const bf16* a1 = a0 + 16;
  const bf16* wb = wpanel + (size_t)(wave & 1) * 4 * 512 + (size_t)lane * 8;

  load_lds16(a0, sA + tid * 8); load_lds16(a1, sA + (256 + tid) * 8);
  a0 += 32; a1 += 32;
  bf16x8 wfc[4], wfn[4];
#pragma unroll
  for (int j = 0; j < 4; ++j)
    wfc[j] = *(const bf16x8*)(wb + (size_t)j * 512);

#pragma unroll 2
  for (int kt = 0; kt < KT32; ++kt) {
    __syncthreads();
    const int cur = kt & 1, nxt = cur ^ 1;
    if (kt + 1 < KT32) {
      load_lds16(a0, sA + (nxt * 512 + tid) * 8);
      load_lds16(a1, sA + (nxt * 512 + 256 + tid) * 8);
      a0 += 32; a1 += 32;
      const bf16* wn = wb + (size_t)(kt + 1) * TILE_ELEMS;
#pragma unroll
      for (int j = 0; j < 4; ++j)
        wfn[j] = *(const bf16x8*)(wn + (size_t)j * 512);
    }
    const bf16* sAc = sA + cur * 4096;
    bf16x8 xf[4];
#pragma unroll
    for (int i = 0; i < 4; ++i)
      xf[i] = *(const bf16x8*)(sAc + ((size_t)quad * 128 + rw + i * 16 + l16) * 8);
#pragma unroll
    for (int i = 0; i < 4; ++i)
#pragma unroll
      for (int j = 0; j < 4; ++j)
        acc[i][j] = __builtin_amdgcn_mfma_f32_16x16x32_bf16(wfc[j], xf[i], acc[i][j], 0, 0, 0);
#pragma unroll
    for (int j = 0; j < 4; ++j) wfc[j] = wfn[j];
  }
}

// output projection: fp32 out, fused bias.  grid: x = m-tile (64), y = n-tile (16)
__global__ __launch_bounds__(256) void gemm_out(
    const bf16* __restrict__ A, const bf16* __restrict__ wpack,
    const float* __restrict__ bo, float* __restrict__ out) {
  __shared__ alignas(16) bf16 sA[2 * 4096];
  const int m0 = blockIdx.x * 128, n0 = blockIdx.y * 128;
  f32x4 acc[4][4];
  gemm_core_lds(A, wpack + (size_t)blockIdx.y * KT32 * TILE_ELEMS, m0, sA, acc);

  const int tid = threadIdx.x, wave = tid >> 6, lane = tid & 63;
  const int quad = lane >> 4, l16 = lane & 15;
  const int rw = (wave >> 1) * 64, cw = (wave & 1) * 64;
#pragma unroll
  for (int i = 0; i < 4; ++i) {
    int m = m0 + rw + i * 16 + l16;
#pragma unroll
    for (int j = 0; j < 4; ++j) {
      int n = n0 + cw + j * 16 + quad * 4;
      f32x4 v = acc[i][j];
#pragma unroll
      for (int r = 0; r < 4; ++r) v[r] += bo[n + r];
      *(f32x4*)(out + (size_t)m * DMODEL + n) = v;
    }
  }
}

// ---------------- flash attention ----------------
// R13: 4 waves x 32 q-rows (2 q-sets), KVBLK=64 as 4x16-k sub-chunks
// (sc live range = 8 VGPR). PV per 32-k pair. Per-lane defer-max fast path;
// per-lane partial l_i reduced once after the kv loop. kf/vf read once feed
// both q-sets. LDS: sK 16 + sV 16 + sP 8 = 40KB.
// NO min-wave launch bound: R12's (256,4) forced a 64-VGPR allocation that
// spilled the o[2][8] accumulators to scratch (+88MB HBM traffic, 275us).
// Natural ~120 VGPR -> 4 waves/SIMD from the hardware occupancy table.
__global__ __launch_bounds__(256) void flash_kernel(
    const bf16* __restrict__ qc, const bf16* __restrict__ kcg,
    const bf16* __restrict__ vcg, bf16* __restrict__ ob) {
  __shared__ alignas(16) bf16 sK[16 * 64 * 8];   // 16KB [kc][s][8]
  __shared__ alignas(16) bf16 sV[8 * 128 * 8];   // 16KB [scl][d][8]
  __shared__ alignas(16) bf16 sP[4 * 1024];      // 8KB: per wave 1KB (2qs x 512)

  const int tid = threadIdx.x, wave = tid >> 6, lane = tid & 63;
  const int quad = lane >> 4, l16 = lane & 15;
  const int bh = blockIdx.y;
  const int q0 = blockIdx.x * 128;               // block covers 128 q-rows

  const bf16* Qg = qc  + (size_t)bh * BH_STRIDE;
  const bf16* Kg = kcg + (size_t)bh * BH_STRIDE;
  const bf16* Vg = vcg + (size_t)bh * BH_STRIDE;

  // Q fragments straight from global (loop-invariant, 32 VGPR)
  bf16x8 qf[2][4];
#pragma unroll
  for (int qs = 0; qs < 2; ++qs)
#pragma unroll
    for (int ks = 0; ks < 4; ++ks)
      qf[qs][ks] = *(const bf16x8*)(Qg + (size_t)(ks * 4 + quad) * (S_TOK * 8)
                                       + (size_t)(q0 + wave * 32 + qs * 16 + l16) * 8);

  bf16* sPw = sP + wave * 1024;

  float m_i[2] = {-1e30f, -1e30f};
  float l_i[2] = {0.f, 0.f};               // per-lane partial row sums
  f32x4 o[2][8];
  const f32x4 zero = {0.f, 0.f, 0.f, 0.f};
#pragma unroll
  for (int qs = 0; qs < 2; ++qs)
#pragma unroll
    for (int dt = 0; dt < 8; ++dt) o[qs][dt] = zero;

#pragma unroll 1
  for (int kv = 0; kv < S_TOK; kv += 64) {
    __syncthreads();
#pragma unroll
    for (int r = 0; r < 4; ++r) {
      int c = r * 256 + tid;
      load_lds16(Kg + (size_t)(c >> 6) * (S_TOK * 8) + (size_t)(kv + (c & 63)) * 8,
                 sK + (size_t)c * 8);
    }
#pragma unroll
    for (int r = 0; r < 4; ++r) {
      int c = r * 256 + tid;
      load_lds16(Vg + (size_t)((kv >> 3) + (c >> 7)) * (HDIM * 8) + (size_t)(c & 127) * 8,
                 sV + (size_t)c * 8);
    }
    __syncthreads();

#pragma unroll
    for (int pp = 0; pp < 2; ++pp) {       // 32-k PV pair
#pragma unroll
      for (int sub = 0; sub < 2; ++sub) {  // 16-k QK/softmax sub-chunk
        const int ch = pp * 2 + sub;
        f32x4 sc0 = zero, sc1 = zero;
        __builtin_amdgcn_s_setprio(1);
#pragma unroll
        for (int ks = 0; ks < 4; ++ks) {
          bf16x8 kf = *(const bf16x8*)(sK + ((size_t)(ks * 4 + quad) * 64 + ch * 16 + l16) * 8);
          sc0 = __builtin_amdgcn_mfma_f32_16x16x32_bf16(kf, qf[0][ks], sc0, 0, 0, 0);
          sc1 = __builtin_amdgcn_mfma_f32_16x16x32_bf16(kf, qf[1][ks], sc1, 0, 0, 0);
        }
        __builtin_amdgcn_s_setprio(0);

        // per-LANE max (no shfl on fast path)
        float t0 = fmaxf(fmaxf(sc0[0], sc0[1]), fmaxf(sc0[2], sc0[3]));
        float t1 = fmaxf(fmaxf(sc1[0], sc1[1]), fmaxf(sc1[2], sc1[3]));
        bool ok = (t0 - m_i[0] <= 8.0f) && (t1 - m_i[1] <= 8.0f);
        if (!__all(ok)) {
          // rare: full row-max across quads, rescale running state
          float r0 = fmaxf(t0, __shfl_xor(t0, 16)); r0 = fmaxf(r0, __shfl_xor(r0, 32));
          float r1 = fmaxf(t1, __shfl_xor(t1, 16)); r1 = fmaxf(r1, __shfl_xor(r1, 32));
          float m0n = fmaxf(m_i[0], r0), a0 = __builtin_amdgcn_exp2f(m_i[0] - m0n);
          float m1n = fmaxf(m_i[1], r1), a1 = __builtin_amdgcn_exp2f(m_i[1] - m1n);
          m_i[0] = m0n; m_i[1] = m1n;
          l_i[0] *= a0; l_i[1] *= a1;
#pragma unroll
          for (int dt = 0; dt < 8; ++dt) { o[0][dt] = o[0][dt] * a0; o[1][dt] = o[1][dt] * a1; }
        }

        // exp + per-lane partial sum + P store (P bounded by 2^8)
        bf16x4 pv0, pv1;
        float s00, s01, s10, s11;
        {
          float p0 = __builtin_amdgcn_exp2f(sc0[0] - m_i[0]);
          float p1 = __builtin_amdgcn_exp2f(sc0[1] - m_i[0]);
          float p2 = __builtin_amdgcn_exp2f(sc0[2] - m_i[0]);
          float p3 = __builtin_amdgcn_exp2f(sc0[3] - m_i[0]);
          pv0[0] = (bf16)p0; pv0[1] = (bf16)p1; pv0[2] = (bf16)p2; pv0[3] = (bf16)p3;
          s00 = p0 + p1; s01 = p2 + p3;
        }
        {
          float p0 = __builtin_amdgcn_exp2f(sc1[0] - m_i[1]);
          float p1 = __builtin_amdgcn_exp2f(sc1[1] - m_i[1]);
          float p2 = __builtin_amdgcn_exp2f(sc1[2] - m_i[1]);
          float p3 = __builtin_amdgcn_exp2f(sc1[3] - m_i[1]);
          pv1[0] = (bf16)p0; pv1[1] = (bf16)p1; pv1[2] = (bf16)p2; pv1[3] = (bf16)p3;
          s10 = p0 + p1; s11 = p2 + p3;
        }
        l_i[0] += s00 + s01;
        l_i[1] += s10 + s11;
        const int prow = (sub * 2 + (quad >> 1)) * 128 + l16 * 8 + (quad & 1) * 4;
        *(bf16x4*)(sPw + prow) = pv0;
        *(bf16x4*)(sPw + 512 + prow) = pv1;
      }

      // PV over the 32-k pair: vf read once, feeds both q-sets
      bf16x8 pf0 = *(const bf16x8*)(sPw + (size_t)(quad * 128 + l16 * 8));
      bf16x8 pf1 = *(const bf16x8*)(sPw + 512 + (size_t)(quad * 128 + l16 * 8));
      __builtin_amdgcn_s_setprio(1);
#pragma unroll
      for (int dt = 0; dt < 8; ++dt) {
        bf16x8 vf = *(const bf16x8*)(sV + ((size_t)(pp * 4 + quad) * 128 + dt * 16 + l16) * 8);
        o[0][dt] = __builtin_amdgcn_mfma_f32_16x16x32_bf16(vf, pf0, o[0][dt], 0, 0, 0);
        o[1][dt] = __builtin_amdgcn_mfma_f32_16x16x32_bf16(vf, pf1, o[1][dt], 0, 0, 0);
      }
      __builtin_amdgcn_s_setprio(0);
    }
  }

  // final cross-quad row-sum (the ONLY shuffles on the softmax fast path)
  int b = bh >> 4, h = bh & 15;
#pragma unroll
  for (int qs = 0; qs < 2; ++qs) {
    float l = l_i[qs];
    l += __shfl_xor(l, 16);
    l += __shfl_xor(l, 32);
    float inv = 1.0f / l;
    int s = q0 + wave * 32 + qs * 16 + l16;
    bf16* orow = ob + ((size_t)(b * S_TOK + s) * DMODEL + h * HDIM);
#pragma unroll
    for (int dt = 0; dt < 8; ++dt) {
      bf16x4 v;
#pragma unroll
      for (int r = 0; r < 4; ++r) v[r] = (bf16)(o[qs][dt][r] * inv);
      *(bf16x4*)(orow + dt * 16 + quad * 4) = v;
    }
  }
}

// ---------------- launch ----------------

extern "C" void kernel_launch(void* const* d_in, const int* in_sizes, int n_in,
                              void* d_out, int out_size, void* d_ws, size_t ws_size,
                              hipStream_t stream) {
  const float* x  = (const float*)d_in[0];
  const float* Wq = (const float*)d_in[2];
  const float* bq = (const float*)d_in[3];
  const float* Wk = (const float*)d_in[4];
  const float* bk = (const float*)d_in[5];
  const float* Wv = (const float*)d_in[6];
  const float* bv = (const float*)d_in[7];
  const float* Wo = (const float*)d_in[8];
  const float* bo = (const float*)d_in[9];
  float* out = (float*)d_out;

  const size_t M = 4 * (size_t)S_TOK;          // 8192
  const size_t SZ_TOK = M * DMODEL * 2;        // 33.5MB bf16 token-shaped buffer
  const size_t SZ_WMAT = (size_t)16 * KT32 * TILE_ELEMS * 2;

  char* p = (char*)d_ws;
  bf16* ap  = (bf16*)p; p += SZ_TOK;           // packed activations; reused as ob
  bf16* wp  = (bf16*)p; p += 3 * SZ_WMAT;      // packed Wq|Wk|Wv
  bf16* wop = (bf16*)p; p += SZ_WMAT;          // packed Wo
  bf16* qc  = (bf16*)p; p += SZ_TOK;
  bf16* kc  = (bf16*)p; p += SZ_TOK;
  bf16* vb  = (bf16*)p; p += SZ_TOK;
  bf16* vc  = (bf16*)p; p += SZ_TOK;
  bf16* ob  = ap;   // apack dead after gemm_qkv; flash writes ob here

  pack_a<<<dim3(64, 64), 256, 0, stream>>>(x, ap);
  pack_w<<<dim3(KT32, 16), 256, 0, stream>>>(Wq, wp);
  pack_w<<<dim3(KT32, 16), 256, 0, stream>>>(Wk, wp + SZ_WMAT / 2);
  pack_w<<<dim3(KT32, 16), 256, 0, stream>>>(Wv, wp + SZ_WMAT);
  pack_w<<<dim3(KT32, 16), 256, 0, stream>>>(Wo, wop);

  gemm_qkv<<<dim3(768), dim3(512), 0, stream>>>(ap, wp, bq, bk, bv, qc, kc, vb);
  v_chunk<<<dim3(32, 64), 256, 0, stream>>>(vb, vc);
  flash_kernel<<<dim3(16, 64), 256, 0, stream>>>(qc, kc, vc, ob);
  gemm_out<<<dim3(64, 16), 256, 0, stream>>>(ob, wop, bo, out);
}

// Round 7
// 631.762 us; speedup vs baseline: 1.2359x; 1.0962x over previous
//
#include <hip/hip_runtime.h>

// Full MHA: x->QKV proj (bf16 MFMA GEMM) -> flash attention -> out proj.
// bf16 compute, fp32 accumulate.
// R14: gemm_out ported to the R8 256x256 3-buf counted-vmcnt pipeline.
//      flash epilogue now writes its output DIRECTLY in pack_a fragment-
//      linear layout (same 8B stores, just remapped addresses) -> gemm_out
//      consumes packed A exactly like gemm_qkv (byte-for-byte clone of the
//      pipeline; fp32+bias epilogue; grid 256 = 8 XCD x 32, bijective swz).
//      Old R5 gemm_core_lds (m97-structure, ~900 TF ceiling) deleted.
//      Flash compute untouched (R13: 200us, VGPR 112, no spill).
// R13: flash 2-q-set reuse + natural VGPR (112) -> 200us.
// R9:  QSCALE folded into Q, Q direct->VGPR, defer-max (T13), setprio (T5).
// R8:  gemm_qkv 256x256 3-buf counted-vmcnt pipeline (T3+T4+T5).

typedef __bf16 bf16;
typedef __bf16 bf16x4 __attribute__((ext_vector_type(4)));
typedef __bf16 bf16x8 __attribute__((ext_vector_type(8)));
typedef float  f32x4  __attribute__((ext_vector_type(4)));

#define S_TOK 2048
#define DMODEL 2048
#define NHEAD 16
#define HDIM 128
#define BH_STRIDE ((size_t)S_TOK * HDIM)   // 262144 elems per (b,h)
#define KT32 (DMODEL / 32)                 // 64 32-k tiles per K
#define TILE_ELEMS 4096                    // 128(m|n) x 32k fragment-linear tile
// 1/sqrt(128) * log2(e) -- folded into Q so flash scores are already log2-scaled
#define QSCALE (0.08838834764831845f * 1.4426950408889634f)

__device__ __forceinline__ void load_lds16(const void* g, void* l) {
  __builtin_amdgcn_global_load_lds((const __attribute__((address_space(1))) void*)g,
                                   (__attribute__((address_space(3))) void*)l,
                                   16, 0, 0);
}

// ---------------- prep kernels ----------------

// Pack x fp32 [8192][2048] -> fragment-linear bf16 tiles:
// apack[(mt*64+kt)*4096 + f*512 + lane*8 + e]
//   = (bf16) x[mt*128 + f*16 + (lane&15)][kt*32 + (lane>>4)*8 + e]
// grid: x = kt (64), y = mt (64)
__global__ __launch_bounds__(256) void pack_a(const float* __restrict__ X,
                                              bf16* __restrict__ dst) {
  __shared__ bf16 lds[128 * 32];
  const int t = threadIdx.x;
  const int kt = blockIdx.x, mt = blockIdx.y;
  const int k0 = kt * 32, m0 = mt * 128;
  // coalesced read: 128 rows x 32k, 8 threads x float4 per row
#pragma unroll
  for (int p = 0; p < 4; ++p) {
    int r = p * 32 + (t >> 3);           // 0..127
    int c = (t & 7) * 4;                 // 0..28
    float4 v = *(const float4*)(X + (size_t)(m0 + r) * DMODEL + k0 + c);
    lds[r * 32 + c + 0] = (bf16)v.x;
    lds[r * 32 + c + 1] = (bf16)v.y;
    lds[r * 32 + c + 2] = (bf16)v.z;
    lds[r * 32 + c + 3] = (bf16)v.w;
  }
  __syncthreads();
  bf16* out = dst + ((size_t)mt * 64 + kt) * TILE_ELEMS;
#pragma unroll
  for (int u = 0; u < 2; ++u) {
    int c = t * 2 + u;                   // chunk 0..511
    int f = c >> 6, lane = c & 63;
    int l16 = lane & 15, q = lane >> 4;
    bf16x8 v;
#pragma unroll
    for (int e = 0; e < 8; ++e)
      v[e] = lds[(f * 16 + l16) * 32 + q * 8 + e];
    *(bf16x8*)(out + (size_t)c * 8) = v;
  }
}

// Pack W fp32 [K=2048][N=2048] row-major into fragment-linear bf16 tiles:
// dst[(nt*64 + kt)*4096 + i_g*512 + quad*128 + l16*8 + e]
//   = (bf16) W[kt*32 + quad*8 + e][nt*128 + i_g*16 + l16]
__global__ __launch_bounds__(256) void pack_w(const float* __restrict__ W,
                                              bf16* __restrict__ dst) {
  __shared__ bf16 lds[32 * 128];
  const int t = threadIdx.x;
  const int kt = blockIdx.x, nt = blockIdx.y;
  const int k0 = kt * 32, n0 = nt * 128;
#pragma unroll
  for (int p = 0; p < 4; ++p) {
    int kl = (t >> 5) + p * 8;
    int nl = (t & 31) * 4;
    float4 v = *(const float4*)(W + (size_t)(k0 + kl) * DMODEL + n0 + nl);
    lds[kl * 128 + nl + 0] = (bf16)v.x;
    lds[kl * 128 + nl + 1] = (bf16)v.y;
    lds[kl * 128 + nl + 2] = (bf16)v.z;
    lds[kl * 128 + nl + 3] = (bf16)v.w;
  }
  __syncthreads();
  bf16* out = dst + ((size_t)nt * KT32 + kt) * TILE_ELEMS;
#pragma unroll
  for (int u = 0; u < 2; ++u) {
    int c = t * 2 + u;
    int i_g = c >> 6, quad = (c >> 4) & 3, l16 = c & 15;
    bf16x8 v;
#pragma unroll
    for (int e = 0; e < 8; ++e)
      v[e] = lds[(quad * 8 + e) * 128 + i_g * 16 + l16];
    *(bf16x8*)(out + (size_t)c * 8) = v;
  }
}

// V reshuffle: vb[bh][s][d] -> vc[bh][s>>3][d][s&7]
__global__ __launch_bounds__(256) void v_chunk(const bf16* __restrict__ vb,
                                               bf16* __restrict__ vc) {
  __shared__ alignas(16) bf16 t[64 * 128];
  const int tid = threadIdx.x;
  const int s0 = blockIdx.x * 64;
  const size_t bhoff = (size_t)blockIdx.y * BH_STRIDE;
  const bf16* src = vb + bhoff + (size_t)s0 * HDIM;
#pragma unroll
  for (int r = 0; r < 4; ++r) {
    int c = r * 256 + tid;
    *(bf16x8*)(t + (size_t)c * 8) = *(const bf16x8*)(src + (size_t)(c >> 4) * HDIM + (c & 15) * 8);
  }
  __syncthreads();
  bf16* dst = vc + bhoff + (size_t)(s0 >> 3) * (HDIM * 8);
#pragma unroll
  for (int r = 0; r < 4; ++r) {
    int c = r * 256 + tid;
    int scl = c >> 7, d = c & 127;
    bf16x8 v;
#pragma unroll
    for (int e = 0; e < 8; ++e) v[e] = t[(size_t)(scl * 8 + e) * HDIM + d];
    *(bf16x8*)(dst + (size_t)scl * (HDIM * 8) + d * 8) = v;
  }
}

// ---------------- gemm_qkv: 256x256 LDS-staged counted-vmcnt pipeline ----------------
// A,B pre-packed fragment-linear (pack_a / pack_w). 8 waves: wm=wave>>2 (2),
// wn=wave&3 (4); per-wave output 128x64 -> acc[8][4] f32x4.
// LDS: 3 buffers x 16384 elems (A: 2x4096 | B: 2x4096). Prefetch distance 2.
// grid: 768 blocks (32 m-tiles x 24 n-tiles), XCD-bijective swizzle.
__global__ __launch_bounds__(512, 2) void gemm_qkv(
    const bf16* __restrict__ apack, const bf16* __restrict__ wpack,
    const float* __restrict__ bq, const float* __restrict__ bk, const float* __restrict__ bv,
    bf16* __restrict__ qc, bf16* __restrict__ kc_, bf16* __restrict__ vb) {
  __shared__ alignas(16) bf16 sBuf[3 * 16384];   // 96 KB
  const int tid = threadIdx.x, wave = tid >> 6, lane = tid & 63;
  const int quad = lane >> 4, l16 = lane & 15;
  const int wm = wave >> 2, wn = wave & 3;

  // XCD-bijective swizzle: 768 wgs = 8 XCDs x 96. Each XCD walks 32 m-tiles
  // per n-panel, 3 consecutive n-panels (3 MB of packed B <= 4 MB XCD L2).
  const int lin = blockIdx.x;
  const int swz = (lin & 7) * 96 + (lin >> 3);
  const int mt = swz & 31, nt = swz >> 5;
  const int m0 = mt * 256, n0 = nt * 256;

  const bf16* srcA0 = apack + (size_t)(mt * 2 + 0) * KT32 * TILE_ELEMS + (size_t)tid * 8;
  const bf16* srcA1 = apack + (size_t)(mt * 2 + 1) * KT32 * TILE_ELEMS + (size_t)tid * 8;
  const bf16* srcB0 = wpack + (size_t)(nt * 2 + 0) * KT32 * TILE_ELEMS + (size_t)tid * 8;
  const bf16* srcB1 = wpack + (size_t)(nt * 2 + 1) * KT32 * TILE_ELEMS + (size_t)tid * 8;

  f32x4 acc[8][4];
  const f32x4 zero = {0.f, 0.f, 0.f, 0.f};
#pragma unroll
  for (int i = 0; i < 8; ++i)
#pragma unroll
    for (int j = 0; j < 4; ++j) acc[i][j] = zero;

  bf16* sD = sBuf + (size_t)tid * 8;   // per-thread staging dst (wave-uniform base + lane*16)

  // prologue: stage K-steps 0 -> buf0, 1 -> buf1 (8 loads outstanding)
  load_lds16(srcA0, sD);
  load_lds16(srcA1, sD + 4096);
  load_lds16(srcB0, sD + 8192);
  load_lds16(srcB1, sD + 12288);
  load_lds16(srcA0 + TILE_ELEMS, sD + 16384);
  load_lds16(srcA1 + TILE_ELEMS, sD + 16384 + 4096);
  load_lds16(srcB0 + TILE_ELEMS, sD + 16384 + 8192);
  load_lds16(srcB1 + TILE_ELEMS, sD + 16384 + 12288);

  // per-wave LDS fragment bases (lane-contiguous ds_read_b128, conflict-free)
  const bf16* ldsA = sBuf + (size_t)wm * 4096 + (size_t)lane * 8;
  const bf16* ldsB = sBuf + 8192 + (size_t)(wn >> 1) * 4096
                   + (size_t)((wn & 1) * 4) * 512 + (size_t)lane * 8;

  int buf = 0, nbuf = 2;
#pragma unroll 1
  for (int t = 0; t < KT32; ++t) {
    if (t == KT32 - 1) { asm volatile("s_waitcnt vmcnt(0)" ::: "memory"); }
    else               { asm volatile("s_waitcnt vmcnt(4)" ::: "memory"); }
    __builtin_amdgcn_s_barrier();
    asm volatile("" ::: "memory");   // keep LDS reads below the barrier

    const bf16* bA = ldsA + buf * 16384;
    const bf16* bB = ldsB + buf * 16384;

    bf16x8 bfr[4], afr[4];
#pragma unroll
    for (int j = 0; j < 4; ++j) bfr[j] = *(const bf16x8*)(bB + (size_t)j * 512);
#pragma unroll
    for (int i = 0; i < 4; ++i) afr[i] = *(const bf16x8*)(bA + (size_t)i * 512);
    if (t < KT32 - 2) {            // stage A-half of K-step t+2
      bf16* d = sD + nbuf * 16384;
      load_lds16(srcA0 + (size_t)(t + 2) * TILE_ELEMS, d);
      load_lds16(srcA1 + (size_t)(t + 2) * TILE_ELEMS, d + 4096);
    }
    __builtin_amdgcn_s_setprio(1);
#pragma unroll
    for (int i = 0; i < 4; ++i)
#pragma unroll
      for (int j = 0; j < 4; ++j)
        acc[i][j] = __builtin_amdgcn_mfma_f32_16x16x32_bf16(bfr[j], afr[i], acc[i][j], 0, 0, 0);
    __builtin_amdgcn_s_setprio(0);

#pragma unroll
    for (int i = 0; i < 4; ++i) afr[i] = *(const bf16x8*)(bA + (size_t)(4 + i) * 512);
    if (t < KT32 - 2) {            // stage B-half of K-step t+2
      bf16* d = sD + nbuf * 16384;
      load_lds16(srcB0 + (size_t)(t + 2) * TILE_ELEMS, d + 8192);
      load_lds16(srcB1 + (size_t)(t + 2) * TILE_ELEMS, d + 12288);
    }
    __builtin_amdgcn_s_setprio(1);
#pragma unroll
    for (int i = 0; i < 4; ++i)
#pragma unroll
      for (int j = 0; j < 4; ++j)
        acc[4 + i][j] = __builtin_amdgcn_mfma_f32_16x16x32_bf16(bfr[j], afr[i], acc[4 + i][j], 0, 0, 0);
    __builtin_amdgcn_s_setprio(0);

    buf  = (buf  == 2) ? 0 : buf  + 1;
    nbuf = (nbuf == 2) ? 0 : nbuf + 1;
  }

  // epilogue (fragment->element mapping verified in R7). Q gets QSCALE folded
  // so flash scores are already in log2 units (saves a VALU mul per score).
  const float* bias; bf16* dst; int chunked; float oscale;
  if (n0 < 2048)      { bias = bq; dst = qc;  chunked = 1; oscale = QSCALE; }
  else if (n0 < 4096) { bias = bk; dst = kc_; chunked = 1; oscale = 1.0f; }
  else                { bias = bv; dst = vb;  chunked = 0; oscale = 1.0f; }
  const int nb = n0 & 2047;
  const int rw = wm * 128, cw = wn * 64;
#pragma unroll
  for (int i = 0; i < 8; ++i) {
    int m = m0 + rw + i * 16 + l16;
    int b = m >> 11, s = m & 2047;
#pragma unroll
    for (int j = 0; j < 4; ++j) {
      int n = nb + cw + j * 16 + quad * 4;
      int h = n >> 7, d = n & 127;
      bf16x4 v;
#pragma unroll
      for (int r = 0; r < 4; ++r) v[r] = (bf16)((acc[i][j][r] + bias[n + r]) * oscale);
      size_t bhoff = (size_t)(b * NHEAD + h) * BH_STRIDE;
      if (chunked)
        *(bf16x4*)(dst + bhoff + (size_t)(d >> 3) * (S_TOK * 8) + (size_t)s * 8 + (d & 7)) = v;
      else
        *(bf16x4*)(dst + bhoff + (size_t)s * HDIM + d) = v;
    }
  }
}

// ---------------- gemm_out: R14 clone of the gemm_qkv pipeline ----------------
// A = flash output, ALREADY fragment-packed (flash epilogue writes pack_a
// layout). B = packed Wo. fp32 output with fused bias.
// grid: 256 blocks (32 m-tiles x 8 n-panels), XCD-bijective swizzle (8x32).
__global__ __launch_bounds__(512, 2) void gemm_out(
    const bf16* __restrict__ apack, const bf16* __restrict__ wpack,
    const float* __restrict__ bo, float* __restrict__ out) {
  __shared__ alignas(16) bf16 sBuf[3 * 16384];   // 96 KB
  const int tid = threadIdx.x, wave = tid >> 6, lane = tid & 63;
  const int quad = lane >> 4, l16 = lane & 15;
  const int wm = wave >> 2, wn = wave & 3;

  const int lin = blockIdx.x;
  const int swz = (lin & 7) * 32 + (lin >> 3);   // 256 = 8 XCD x 32
  const int mt = swz & 31, nt = swz >> 5;        // nt in 0..7

  const bf16* srcA0 = apack + (size_t)(mt * 2 + 0) * KT32 * TILE_ELEMS + (size_t)tid * 8;
  const bf16* srcA1 = apack + (size_t)(mt * 2 + 1) * KT32 * TILE_ELEMS + (size_t)tid * 8;
  const bf16* srcB0 = wpack + (size_t)(nt * 2 + 0) * KT32 * TILE_ELEMS + (size_t)tid * 8;
  const bf16* srcB1 = wpack + (size_t)(nt * 2 + 1) * KT32 * TILE_ELEMS + (size_t)tid * 8;

  f32x4 acc[8][4];
  const f32x4 zero = {0.f, 0.f, 0.f, 0.f};
#pragma unroll
  for (int i = 0; i < 8; ++i)
#pragma unroll
    for (int j = 0; j < 4; ++j) acc[i][j] = zero;

  bf16* sD = sBuf + (size_t)tid * 8;

  load_lds16(srcA0, sD);
  load_lds16(srcA1, sD + 4096);
  load_lds16(srcB0, sD + 8192);
  load_lds16(srcB1, sD + 12288);
  load_lds16(srcA0 + TILE_ELEMS, sD + 16384);
  load_lds16(srcA1 + TILE_ELEMS, sD + 16384 + 4096);
  load_lds16(srcB0 + TILE_ELEMS, sD + 16384 + 8192);
  load_lds16(srcB1 + TILE_ELEMS, sD + 16384 + 12288);

  const bf16* ldsA = sBuf + (size_t)wm * 4096 + (size_t)lane * 8;
  const bf16* ldsB = sBuf + 8192 + (size_t)(wn >> 1) * 4096
                   + (size_t)((wn & 1) * 4) * 512 + (size_t)lane * 8;

  int buf = 0, nbuf = 2;
#pragma unroll 1
  for (int t = 0; t < KT32; ++t) {
    if (t == KT32 - 1) { asm volatile("s_waitcnt vmcnt(0)" ::: "memory"); }
    else               { asm volatile("s_waitcnt vmcnt(4)" ::: "memory"); }
    __builtin_amdgcn_s_barrier();
    asm volatile("" ::: "memory");

    const bf16* bA = ldsA + buf * 16384;
    const bf16* bB = ldsB + buf * 16384;

    bf16x8 bfr[4], afr[4];
#pragma unroll
    for (int j = 0; j < 4; ++j) bfr[j] = *(const bf16x8*)(bB + (size_t)j * 512);
#pragma unroll
    for (int i = 0; i < 4; ++i) afr[i] = *(const bf16x8*)(bA + (size_t)i * 512);
    if (t < KT32 - 2) {
      bf16* d = sD + nbuf * 16384;
      load_lds16(srcA0 + (size_t)(t + 2) * TILE_ELEMS, d);
      load_lds16(srcA1 + (size_t)(t + 2) * TILE_ELEMS, d + 4096);
    }
    __builtin_amdgcn_s_setprio(1);
#pragma unroll
    for (int i = 0; i < 4; ++i)
#pragma unroll
      for (int j = 0; j < 4; ++j)
        acc[i][j] = __builtin_amdgcn_mfma_f32_16x16x32_bf16(bfr[j], afr[i], acc[i][j], 0, 0, 0);
    __builtin_amdgcn_s_setprio(0);

#pragma unroll
    for (int i = 0; i < 4; ++i) afr[i] = *(const bf16x8*)(bA + (size_t)(4 + i) * 512);
    if (t < KT32 - 2) {
      bf16* d = sD + nbuf * 16384;
      load_lds16(srcB0 + (size_t)(t + 2) * TILE_ELEMS, d + 8192);
      load_lds16(srcB1 + (size_t)(t + 2) * TILE_ELEMS, d + 12288);
    }
    __builtin_amdgcn_s_setprio(1);
#pragma unroll
    for (int i = 0; i < 4; ++i)
#pragma unroll
      for (int j = 0; j < 4; ++j)
        acc[4 + i][j] = __builtin_amdgcn_mfma_f32_16x16x32_bf16(bfr[j], afr[i], acc[4 + i][j], 0, 0, 0);
    __builtin_amdgcn_s_setprio(0);

    buf  = (buf  == 2) ? 0 : buf  + 1;
    nbuf = (nbuf == 2) ? 0 : nbuf + 1;
  }

  // fp32 epilogue with fused bias, row-major out
  const int m0 = mt * 256, n0 = nt * 256;
  const int rw = wm * 128, cw = wn * 64;
#pragma unroll
  for (int i = 0; i < 8; ++i) {
    int m = m0 + rw + i * 16 + l16;
#pragma unroll
    for (int j = 0; j < 4; ++j) {
      int n = n0 + cw + j * 16 + quad * 4;
      f32x4 v = acc[i][j];
#pragma unroll
      for (int r = 0; r < 4; ++r) v[r] += bo[n + r];
      *(f32x4*)(out + (size_t)m * DMODEL + n) = v;
    }
  }
}

// ---------------- flash attention ----------------
// R13 core (200us verified). R14: epilogue writes output in pack_a
// fragment-linear layout so gemm_out can consume it directly:
//   packed(m, c) with m = b*2048+s, c = h*128 + dt*16 + quad*4 + r:
//   mt=m>>7, f=(m>>4)&7, l16=m&15; kt=h*4+(dt>>1), q8=(dt*2+(quad>>1))&3,
//   e0=(quad&1)*4  ->  off = (mt*64+kt)*4096 + f*512 + (q8*16+l16)*8 + e0.
//   Same 8B bf16x4 stores as before, remapped addresses only.
__global__ __launch_bounds__(256) void flash_kernel(
    const bf16* __restrict__ qc, const bf16* __restrict__ kcg,
    const bf16* __restrict__ vcg, bf16* __restrict__ obp) {
  __shared__ alignas(16) bf16 sK[16 * 64 * 8];   // 16KB [kc][s][8]
  __shared__ alignas(16) bf16 sV[8 * 128 * 8];   // 16KB [scl][d][8]
  __shared__ alignas(16) bf16 sP[4 * 1024];      // 8KB: per wave 1KB (2qs x 512)

  const int tid = threadIdx.x, wave = tid >> 6, lane = tid & 63;
  const int quad = lane >> 4, l16 = lane & 15;
  const int bh = blockIdx.y;
  const int q0 = blockIdx.x * 128;               // block covers 128 q-rows

  const bf16* Qg = qc  + (size_t)bh * BH_STRIDE;
  const bf16* Kg = kcg + (size_t)bh * BH_STRIDE;
  const bf16* Vg = vcg + (size_t)bh * BH_STRIDE;

  // Q fragments straight from global (loop-invariant, 32 VGPR)
  bf16x8 qf[2][4];
#pragma unroll
  for (int qs = 0; qs < 2; ++qs)
#pragma unroll
    for (int ks = 0; ks < 4; ++ks)
      qf[qs][ks] = *(const bf16x8*)(Qg + (size_t)(ks * 4 + quad) * (S_TOK * 8)
                                       + (size_t)(q0 + wave * 32 + qs * 16 + l16) * 8);

  bf16* sPw = sP + wave * 1024;

  float m_i[2] = {-1e30f, -1e30f};
  float l_i[2] = {0.f, 0.f};               // per-lane partial row sums
  f32x4 o[2][8];
  const f32x4 zero = {0.f, 0.f, 0.f, 0.f};
#pragma unroll
  for (int qs = 0; qs < 2; ++qs)
#pragma unroll
    for (int dt = 0; dt < 8; ++dt) o[qs][dt] = zero;

#pragma unroll 1
  for (int kv = 0; kv < S_TOK; kv += 64) {
    __syncthreads();
#pragma unroll
    for (int r = 0; r < 4; ++r) {
      int c = r * 256 + tid;
      load_lds16(Kg + (size_t)(c >> 6) * (S_TOK * 8) + (size_t)(kv + (c & 63)) * 8,
                 sK + (size_t)c * 8);
    }
#pragma unroll
    for (int r = 0; r < 4; ++r) {
      int c = r * 256 + tid;
      load_lds16(Vg + (size_t)((kv >> 3) + (c >> 7)) * (HDIM * 8) + (size_t)(c & 127) * 8,
                 sV + (size_t)c * 8);
    }
    __syncthreads();

#pragma unroll
    for (int pp = 0; pp < 2; ++pp) {       // 32-k PV pair
#pragma unroll
      for (int sub = 0; sub < 2; ++sub) {  // 16-k QK/softmax sub-chunk
        const int ch = pp * 2 + sub;
        f32x4 sc0 = zero, sc1 = zero;
        __builtin_amdgcn_s_setprio(1);
#pragma unroll
        for (int ks = 0; ks < 4; ++ks) {
          bf16x8 kf = *(const bf16x8*)(sK + ((size_t)(ks * 4 + quad) * 64 + ch * 16 + l16) * 8);
          sc0 = __builtin_amdgcn_mfma_f32_16x16x32_bf16(kf, qf[0][ks], sc0, 0, 0, 0);
          sc1 = __builtin_amdgcn_mfma_f32_16x16x32_bf16(kf, qf[1][ks], sc1, 0, 0, 0);
        }
        __builtin_amdgcn_s_setprio(0);

        // per-LANE max (no shfl on fast path)
        float t0 = fmaxf(fmaxf(sc0[0], sc0[1]), fmaxf(sc0[2], sc0[3]));
        float t1 = fmaxf(fmaxf(sc1[0], sc1[1]), fmaxf(sc1[2], sc1[3]));
        bool ok = (t0 - m_i[0] <= 8.0f) && (t1 - m_i[1] <= 8.0f);
        if (!__all(ok)) {
          // rare: full row-max across quads, rescale running state
          float r0 = fmaxf(t0, __shfl_xor(t0, 16)); r0 = fmaxf(r0, __shfl_xor(r0, 32));
          float r1 = fmaxf(t1, __shfl_xor(t1, 16)); r1 = fmaxf(r1, __shfl_xor(r1, 32));
          float m0n = fmaxf(m_i[0], r0), a0 = __builtin_amdgcn_exp2f(m_i[0] - m0n);
          float m1n = fmaxf(m_i[1], r1), a1 = __builtin_amdgcn_exp2f(m_i[1] - m1n);
          m_i[0] = m0n; m_i[1] = m1n;
          l_i[0] *= a0; l_i[1] *= a1;
#pragma unroll
          for (int dt = 0; dt < 8; ++dt) { o[0][dt] = o[0][dt] * a0; o[1][dt] = o[1][dt] * a1; }
        }

        // exp + per-lane partial sum + P store (P bounded by 2^8)
        bf16x4 pv0, pv1;
        float s00, s01, s10, s11;
        {
          float p0 = __builtin_amdgcn_exp2f(sc0[0] - m_i[0]);
          float p1 = __builtin_amdgcn_exp2f(sc0[1] - m_i[0]);
          float p2 = __builtin_amdgcn_exp2f(sc0[2] - m_i[0]);
          float p3 = __builtin_amdgcn_exp2f(sc0[3] - m_i[0]);
          pv0[0] = (bf16)p0; pv0[1] = (bf16)p1; pv0[2] = (bf16)p2; pv0[3] = (bf16)p3;
          s00 = p0 + p1; s01 = p2 + p3;
        }
        {
          float p0 = __builtin_amdgcn_exp2f(sc1[0] - m_i[1]);
          float p1 = __builtin_amdgcn_exp2f(sc1[1] - m_i[1]);
          float p2 = __builtin_amdgcn_exp2f(sc1[2] - m_i[1]);
          float p3 = __builtin_amdgcn_exp2f(sc1[3] - m_i[1]);
          pv1[0] = (bf16)p0; pv1[1] = (bf16)p1; pv1[2] = (bf16)p2; pv1[3] = (bf16)p3;
          s10 = p0 + p1; s11 = p2 + p3;
        }
        l_i[0] += s00 + s01;
        l_i[1] += s10 + s11;
        const int prow = (sub * 2 + (quad >> 1)) * 128 + l16 * 8 + (quad & 1) * 4;
        *(bf16x4*)(sPw + prow) = pv0;
        *(bf16x4*)(sPw + 512 + prow) = pv1;
      }

      // PV over the 32-k pair: vf read once, feeds both q-sets
      bf16x8 pf0 = *(const bf16x8*)(sPw + (size_t)(quad * 128 + l16 * 8));
      bf16x8 pf1 = *(const bf16x8*)(sPw + 512 + (size_t)(quad * 128 + l16 * 8));
      __builtin_amdgcn_s_setprio(1);
#pragma unroll
      for (int dt = 0; dt < 8; ++dt) {
        bf16x8 vf = *(const bf16x8*)(sV + ((size_t)(pp * 4 + quad) * 128 + dt * 16 + l16) * 8);
        o[0][dt] = __builtin_amdgcn_mfma_f32_16x16x32_bf16(vf, pf0, o[0][dt], 0, 0, 0);
        o[1][dt] = __builtin_amdgcn_mfma_f32_16x16x32_bf16(vf, pf1, o[1][dt], 0, 0, 0);
      }
      __builtin_amdgcn_s_setprio(0);
    }
  }

  // final cross-quad row-sum, then write output in pack_a layout
  const int b = bh >> 4, h = bh & 15;
#pragma unroll
  for (int qs = 0; qs < 2; ++qs) {
    float l = l_i[qs];
    l += __shfl_xor(l, 16);
    l += __shfl_xor(l, 32);
    float inv = 1.0f / l;
    const int m = b * S_TOK + (q0 + wave * 32 + qs * 16 + l16);
    const int mt = m >> 7, f = (m >> 4) & 7;          // m&15 == l16
    bf16* base = obp + (size_t)(mt * 64) * TILE_ELEMS + (size_t)f * 512
               + (size_t)l16 * 8 + (quad & 1) * 4;
#pragma unroll
    for (int dt = 0; dt < 8; ++dt) {
      const int kt = h * 4 + (dt >> 1);
      const int q8 = (dt * 2 + (quad >> 1)) & 3;
      bf16x4 v;
#pragma unroll
      for (int r = 0; r < 4; ++r) v[r] = (bf16)(o[qs][dt][r] * inv);
      *(bf16x4*)(base + (size_t)kt * TILE_ELEMS + (size_t)q8 * 128) = v;
    }
  }
}

// ---------------- launch ----------------

extern "C" void kernel_launch(void* const* d_in, const int* in_sizes, int n_in,
                              void* d_out, int out_size, void* d_ws, size_t ws_size,
                              hipStream_t stream) {
  const float* x  = (const float*)d_in[0];
  const float* Wq = (const float*)d_in[2];
  const float* bq = (const float*)d_in[3];
  const float* Wk = (const float*)d_in[4];
  const float* bk = (const float*)d_in[5];
  const float* Wv = (const float*)d_in[6];
  const float* bv = (const float*)d_in[7];
  const float* Wo = (const float*)d_in[8];
  const float* bo = (const float*)d_in[9];
  float* out = (float*)d_out;

  const size_t M = 4 * (size_t)S_TOK;          // 8192
  const size_t SZ_TOK = M * DMODEL * 2;        // 33.5MB bf16 token-shaped buffer
  const size_t SZ_WMAT = (size_t)16 * KT32 * TILE_ELEMS * 2;

  char* p = (char*)d_ws;
  bf16* ap  = (bf16*)p; p += SZ_TOK;           // packed activations; reused as ob (packed)
  bf16* wp  = (bf16*)p; p += 3 * SZ_WMAT;      // packed Wq|Wk|Wv
  bf16* wop = (bf16*)p; p += SZ_WMAT;          // packed Wo
  bf16* qc  = (bf16*)p; p += SZ_TOK;
  bf16* kc  = (bf16*)p; p += SZ_TOK;
  bf16* vb  = (bf16*)p; p += SZ_TOK;
  bf16* vc  = (bf16*)p; p += SZ_TOK;
  bf16* ob  = ap;   // apack dead after gemm_qkv; flash writes packed output here

  pack_a<<<dim3(64, 64), 256, 0, stream>>>(x, ap);
  pack_w<<<dim3(KT32, 16), 256, 0, stream>>>(Wq, wp);
  pack_w<<<dim3(KT32, 16), 256, 0, stream>>>(Wk, wp + SZ_WMAT / 2);
  pack_w<<<dim3(KT32, 16), 256, 0, stream>>>(Wv, wp + SZ_WMAT);
  pack_w<<<dim3(KT32, 16), 256, 0, stream>>>(Wo, wop);

  gemm_qkv<<<dim3(768), dim3(512), 0, stream>>>(ap, wp, bq, bk, bv, qc, kc, vb);
  v_chunk<<<dim3(32, 64), 256, 0, stream>>>(vb, vc);
  flash_kernel<<<dim3(16, 64), 256, 0, stream>>>(qc, kc, vc, ob);
  gemm_out<<<dim3(256), dim3(512), 0, stream>>>(ob, wop, bo, out);
}